// Round 5
// baseline (99.985 us; speedup 1.0000x reference)
//
#include <hip/hip_runtime.h>
#include <hip/hip_fp16.h>

// NCC (local normalized cross-correlation) loss, 9x9x9 window, zero-pad.
// Volume: [1,1,128,160,192] f32. Output: scalar f32 = 1 - mean(cc).
//
// Separable box filter, fp16x2 intermediates (2 adjacent W-pixels per
// __half2 => every lane moves 4B, full 256B wave coalescing):
//   pass1: W-axis sums of 5 derived channels -> A (half2). 2 lines/block.
//   pass2: H-axis sums A -> B, register-FIFO, h in 4 runs of 40.
//   pass3: D-axis sums + cc + reduce, register-FIFO float2, d in runs of 16.
//   finalize: out = 1 - acc/N.
// ws: A 5*N/2 half2 + B 5*N/2 half2 + acc = 78.6 MB.

#define D_ 128
#define H_ 160
#define W_ 192
#define WP_ (W_ / 2)               // 96 half2 per line
#define HW_ (H_ * W_)
#define N_ (D_ * H_ * W_)          // 3,932,160
#define NH2 (N_ / 2)               // half2 per channel
#define WIN_INV (1.0f / 729.0f)
#define HCH 40                     // h-run length in pass2
#define CH3 16                     // d-run length in pass3

__device__ __forceinline__ float2 h2f(__half2 v) { return __half22float2(v); }
__device__ __forceinline__ __half2 f2h(float x, float y) {
    return __float22half2_rn(make_float2(x, y));
}

// ---------------- pass1: W-axis box sum of 5 derived channels -------------
// Block: 256 threads, 2 consecutive lines. Threads 0..191 compute one
// half2 output pair each (ll = t/96, wp = t%96).
__global__ __launch_bounds__(256) void ncc_pass1(const float* __restrict__ I,
                                                 const float* __restrict__ J,
                                                 __half2* __restrict__ A,
                                                 float* __restrict__ acc) {
    __shared__ float sI[2 * W_];
    __shared__ float sJ[2 * W_];
    const int t = threadIdx.x;
    const int line0 = blockIdx.x * 2;
    const int base = line0 * W_;
    sI[t] = I[base + t];
    sJ[t] = J[base + t];
    if (t < 2 * W_ - 256) { sI[t + 256] = I[base + t + 256]; sJ[t + 256] = J[base + t + 256]; }
    if (blockIdx.x == 0 && t == 0) *acc = 0.0f;
    __syncthreads();
    if (t >= 2 * WP_) return;
    const int ll = t / WP_;
    const int wp = t % WP_;
    const int w0 = 2 * wp;
    const float* a_ = sI + ll * W_;
    const float* b_ = sJ + ll * W_;
    float s1a = 0, s2a = 0, s3a = 0, s4a = 0, s5a = 0;
    float s1b = 0, s2b = 0, s3b = 0, s4b = 0, s5b = 0;
#pragma unroll
    for (int j = -4; j <= 5; ++j) {
        int idx = w0 + j;
        float a = 0.f, b = 0.f;
        if (idx >= 0 && idx < W_) { a = a_[idx]; b = b_[idx]; }
        float p3 = a * a, p4 = b * b, p5 = a * b;
        if (j <= 4) { s1a += a; s2a += b; s3a += p3; s4a += p4; s5a += p5; }
        if (j >= -3) { s1b += a; s2b += b; s3b += p3; s4b += p4; s5b += p5; }
    }
    const int o = (line0 + ll) * WP_ + wp;
    A[0 * NH2 + o] = f2h(s1a, s1b);
    A[1 * NH2 + o] = f2h(s2a, s2b);
    A[2 * NH2 + o] = f2h(s3a, s3b);
    A[3 * NH2 + o] = f2h(s4a, s4b);
    A[4 * NH2 + o] = f2h(s5a, s5b);
}

// -------- pass2: H-axis box sum, A -> B, register-FIFO, chunked h ---------
__global__ __launch_bounds__(256) void ncc_pass2(const __half2* __restrict__ A,
                                                 __half2* __restrict__ B) {
    const int t = blockIdx.x * 256 + threadIdx.x;   // < 5*128*4*96 = 245760
    const int wp = t % WP_;
    const int rest = t / WP_;                       // (c*128 + d)*4 + hc
    const int hc = rest & 3;
    const int rest2 = rest >> 2;
    const int d = rest2 & 127;
    const int c = rest2 >> 7;
    const __half2* colA = A + c * NH2 + d * (H_ * WP_) + wp;
    __half2* colB = B + c * NH2 + d * (H_ * WP_) + wp;
    const int h0 = hc * HCH;

    float2 win[9];
    float Sx = 0.f, Sy = 0.f;
#pragma unroll
    for (int j = 0; j < 9; ++j) {
        int hh = h0 - 4 + j;
        float2 v = ((unsigned)hh < (unsigned)H_) ? h2f(colA[hh * WP_])
                                                 : make_float2(0.f, 0.f);
        win[j] = v; Sx += v.x; Sy += v.y;
    }
#pragma unroll
    for (int i = 0; i < HCH; ++i) {
        int h = h0 + i;
        colB[h * WP_] = f2h(Sx, Sy);
        if (i + 1 < HCH) {
            int hh = h + 5;
            float2 v = (hh < H_) ? h2f(colA[hh * WP_]) : make_float2(0.f, 0.f);
            Sx += v.x - win[0].x; Sy += v.y - win[0].y;
#pragma unroll
            for (int j = 0; j < 8; ++j) win[j] = win[j + 1];
            win[8] = v;
        }
    }
}

// ---- pass3: D-axis box sum + cc + reduce, register-FIFO, chunked d -------
__global__ __launch_bounds__(256) void ncc_pass3(const __half2* __restrict__ B,
                                                 float* __restrict__ acc) {
    const int pp = (blockIdx.x % (HW_ / 512)) * 256 + threadIdx.x;  // pixel pair
    const int d0 = (blockIdx.x / (HW_ / 512)) * CH3;
    const __half2* base = B + pp;

    float2 win[5][9];
    float2 S[5];
    float sum = 0.f;
#pragma unroll
    for (int c = 0; c < 5; ++c) {
        S[c] = make_float2(0.f, 0.f);
#pragma unroll
        for (int j = 0; j < 9; ++j) {
            int dd = d0 - 4 + j;
            float2 v = ((unsigned)dd < (unsigned)D_)
                           ? h2f(base[c * NH2 + dd * (H_ * WP_)])
                           : make_float2(0.f, 0.f);
            win[c][j] = v; S[c].x += v.x; S[c].y += v.y;
        }
    }
#pragma unroll
    for (int i = 0; i < CH3; ++i) {
        {
            float cr = S[4].x - S[1].x * S[0].x * WIN_INV;
            float Iv = S[2].x - S[0].x * S[0].x * WIN_INV;
            float Jv = S[3].x - S[1].x * S[1].x * WIN_INV;
            sum += cr * cr / (Iv * Jv + 1e-5f);
        }
        {
            float cr = S[4].y - S[1].y * S[0].y * WIN_INV;
            float Iv = S[2].y - S[0].y * S[0].y * WIN_INV;
            float Jv = S[3].y - S[1].y * S[1].y * WIN_INV;
            sum += cr * cr / (Iv * Jv + 1e-5f);
        }
        if (i + 1 < CH3) {
            int dd = d0 + i + 5;
            bool ok = dd < D_;                      // wave-uniform
#pragma unroll
            for (int c = 0; c < 5; ++c) {
                float2 v = ok ? h2f(base[c * NH2 + dd * (H_ * WP_)])
                              : make_float2(0.f, 0.f);
                S[c].x += v.x - win[c][0].x;
                S[c].y += v.y - win[c][0].y;
#pragma unroll
                for (int j = 0; j < 8; ++j) win[c][j] = win[c][j + 1];
                win[c][8] = v;
            }
        }
    }

    for (int off = 32; off; off >>= 1) sum += __shfl_down(sum, off, 64);
    __shared__ float wsum[4];
    const int lane = threadIdx.x & 63, wv = threadIdx.x >> 6;
    if (lane == 0) wsum[wv] = sum;
    __syncthreads();
    if (threadIdx.x == 0)
        atomicAdd(acc, wsum[0] + wsum[1] + wsum[2] + wsum[3]);
}

__global__ void ncc_finalize(const float* __restrict__ acc,
                             float* __restrict__ out) {
    out[0] = 1.0f - acc[0] * (1.0f / (float)N_);
}

extern "C" void kernel_launch(void* const* d_in, const int* in_sizes, int n_in,
                              void* d_out, int out_size, void* d_ws, size_t ws_size,
                              hipStream_t stream) {
    const float* I = (const float*)d_in[0];   // y_true
    const float* J = (const float*)d_in[1];   // y_pred
    __half2* A = (__half2*)d_ws;               // 5*NH2
    __half2* B = A + 5 * NH2;                  // 5*NH2
    float* acc = (float*)(B + 5 * NH2);
    float* out = (float*)d_out;

    ncc_pass1<<<D_ * H_ / 2, 256, 0, stream>>>(I, J, A, acc);
    ncc_pass2<<<(5 * D_ * 4 * WP_) / 256, 256, 0, stream>>>(A, B);
    ncc_pass3<<<(HW_ / 512) * (D_ / CH3), 256, 0, stream>>>(B, acc);
    ncc_finalize<<<1, 1, 0, stream>>>(acc, out);
}

// Round 6
// 59.739 us; speedup vs baseline: 1.6737x; 1.6737x over previous
//
#include <hip/hip_runtime.h>
#include <hip/hip_fp16.h>

// NCC (local normalized cross-correlation) loss, 9x9x9 window, zero-pad.
// Volume: [1,1,128,160,192] f32. Output: scalar f32 = 1 - mean(cc).
//
// Separable box filter, fp16x2 intermediates (2 adjacent W-pixels per
// __half2 => every lane moves 4B, full wave coalescing):
//   pass1: W-axis sums of 5 derived channels -> A (half2). 2 lines/block.
//   pass2: H-axis sums A -> B, register-FIFO, h in 4 runs of 40.
//   pass3: D-axis sums + cc + reduce. RELOAD sliding window (no register
//          FIFO): S += lead - trail, trail re-read from L1/L2. Short d-runs
//          (CH3=8) => 960 blocks, ~15 waves/CU for latency hiding.
//   finalize: out = 1 - acc/N.
// ws: A 5*N/2 half2 + B 5*N/2 half2 + acc = 78.6 MB.

#define D_ 128
#define H_ 160
#define W_ 192
#define WP_ (W_ / 2)               // 96 half2 per line
#define HW_ (H_ * W_)
#define HWP_ (HW_ / 2)             // half2 per d-slice
#define N_ (D_ * H_ * W_)          // 3,932,160
#define NH2 (N_ / 2)               // half2 per channel
#define WIN_INV (1.0f / 729.0f)
#define HCH 40                     // h-run length in pass2
#define CH3 8                      // d-run length in pass3

__device__ __forceinline__ float2 h2f(__half2 v) { return __half22float2(v); }
__device__ __forceinline__ __half2 f2h(float x, float y) {
    return __float22half2_rn(make_float2(x, y));
}

// ---------------- pass1: W-axis box sum of 5 derived channels -------------
__global__ __launch_bounds__(256) void ncc_pass1(const float* __restrict__ I,
                                                 const float* __restrict__ J,
                                                 __half2* __restrict__ A,
                                                 float* __restrict__ acc) {
    __shared__ float sI[2 * W_];
    __shared__ float sJ[2 * W_];
    const int t = threadIdx.x;
    const int line0 = blockIdx.x * 2;
    const int base = line0 * W_;
    sI[t] = I[base + t];
    sJ[t] = J[base + t];
    if (t < 2 * W_ - 256) { sI[t + 256] = I[base + t + 256]; sJ[t + 256] = J[base + t + 256]; }
    if (blockIdx.x == 0 && t == 0) *acc = 0.0f;
    __syncthreads();
    if (t >= 2 * WP_) return;
    const int ll = t / WP_;
    const int wp = t % WP_;
    const int w0 = 2 * wp;
    const float* a_ = sI + ll * W_;
    const float* b_ = sJ + ll * W_;
    float s1a = 0, s2a = 0, s3a = 0, s4a = 0, s5a = 0;
    float s1b = 0, s2b = 0, s3b = 0, s4b = 0, s5b = 0;
#pragma unroll
    for (int j = -4; j <= 5; ++j) {
        int idx = w0 + j;
        float a = 0.f, b = 0.f;
        if (idx >= 0 && idx < W_) { a = a_[idx]; b = b_[idx]; }
        float p3 = a * a, p4 = b * b, p5 = a * b;
        if (j <= 4) { s1a += a; s2a += b; s3a += p3; s4a += p4; s5a += p5; }
        if (j >= -3) { s1b += a; s2b += b; s3b += p3; s4b += p4; s5b += p5; }
    }
    const int o = (line0 + ll) * WP_ + wp;
    A[0 * NH2 + o] = f2h(s1a, s1b);
    A[1 * NH2 + o] = f2h(s2a, s2b);
    A[2 * NH2 + o] = f2h(s3a, s3b);
    A[3 * NH2 + o] = f2h(s4a, s4b);
    A[4 * NH2 + o] = f2h(s5a, s5b);
}

// -------- pass2: H-axis box sum, A -> B, register-FIFO, chunked h ---------
__global__ __launch_bounds__(256) void ncc_pass2(const __half2* __restrict__ A,
                                                 __half2* __restrict__ B) {
    const int t = blockIdx.x * 256 + threadIdx.x;   // < 5*128*4*96 = 245760
    const int wp = t % WP_;
    const int rest = t / WP_;                       // (c*128 + d)*4 + hc
    const int hc = rest & 3;
    const int rest2 = rest >> 2;
    const int d = rest2 & 127;
    const int c = rest2 >> 7;
    const __half2* colA = A + c * NH2 + d * (H_ * WP_) + wp;
    __half2* colB = B + c * NH2 + d * (H_ * WP_) + wp;
    const int h0 = hc * HCH;

    float2 win[9];
    float Sx = 0.f, Sy = 0.f;
#pragma unroll
    for (int j = 0; j < 9; ++j) {
        int hh = h0 - 4 + j;
        float2 v = ((unsigned)hh < (unsigned)H_) ? h2f(colA[hh * WP_])
                                                 : make_float2(0.f, 0.f);
        win[j] = v; Sx += v.x; Sy += v.y;
    }
#pragma unroll
    for (int i = 0; i < HCH; ++i) {
        int h = h0 + i;
        colB[h * WP_] = f2h(Sx, Sy);
        if (i + 1 < HCH) {
            int hh = h + 5;
            float2 v = (hh < H_) ? h2f(colA[hh * WP_]) : make_float2(0.f, 0.f);
            Sx += v.x - win[0].x; Sy += v.y - win[0].y;
#pragma unroll
            for (int j = 0; j < 8; ++j) win[j] = win[j + 1];
            win[8] = v;
        }
    }
}

// ---- pass3: D-axis box sum + cc + reduce, RELOAD sliding window ----------
// Thread -> (pixel-pair pp, d-run of CH3). No FIFO: trailing tap re-read
// from cache. All predicates wave-uniform (depend only on d).
__global__ __launch_bounds__(256) void ncc_pass3(const __half2* __restrict__ B,
                                                 float* __restrict__ acc) {
    const int pp = (blockIdx.x % (HWP_ / 256)) * 256 + threadIdx.x;
    const int d0 = (blockIdx.x / (HWP_ / 256)) * CH3;
    const __half2* base = B + pp;

    float2 S[5];
    float sum = 0.f;
#pragma unroll
    for (int c = 0; c < 5; ++c) S[c] = make_float2(0.f, 0.f);
#pragma unroll
    for (int j = -4; j <= 4; ++j) {
        int dd = d0 + j;
        if ((unsigned)dd < (unsigned)D_) {
#pragma unroll
            for (int c = 0; c < 5; ++c) {
                float2 v = h2f(base[c * NH2 + dd * HWP_]);
                S[c].x += v.x; S[c].y += v.y;
            }
        }
    }
#pragma unroll
    for (int i = 0; i < CH3; ++i) {
        {
            float cr = S[4].x - S[1].x * S[0].x * WIN_INV;
            float Iv = S[2].x - S[0].x * S[0].x * WIN_INV;
            float Jv = S[3].x - S[1].x * S[1].x * WIN_INV;
            sum += cr * cr / (Iv * Jv + 1e-5f);
        }
        {
            float cr = S[4].y - S[1].y * S[0].y * WIN_INV;
            float Iv = S[2].y - S[0].y * S[0].y * WIN_INV;
            float Jv = S[3].y - S[1].y * S[1].y * WIN_INV;
            sum += cr * cr / (Iv * Jv + 1e-5f);
        }
        if (i + 1 < CH3) {
            int dl = d0 + i + 5;                    // new leading tap
            int dt = d0 + i - 4;                    // expiring trailing tap
            if (dl < D_) {
#pragma unroll
                for (int c = 0; c < 5; ++c) {
                    float2 v = h2f(base[c * NH2 + dl * HWP_]);
                    S[c].x += v.x; S[c].y += v.y;
                }
            }
            if (dt >= 0) {
#pragma unroll
                for (int c = 0; c < 5; ++c) {
                    float2 v = h2f(base[c * NH2 + dt * HWP_]);
                    S[c].x -= v.x; S[c].y -= v.y;
                }
            }
        }
    }

    for (int off = 32; off; off >>= 1) sum += __shfl_down(sum, off, 64);
    __shared__ float wsum[4];
    const int lane = threadIdx.x & 63, wv = threadIdx.x >> 6;
    if (lane == 0) wsum[wv] = sum;
    __syncthreads();
    if (threadIdx.x == 0)
        atomicAdd(acc, wsum[0] + wsum[1] + wsum[2] + wsum[3]);
}

__global__ void ncc_finalize(const float* __restrict__ acc,
                             float* __restrict__ out) {
    out[0] = 1.0f - acc[0] * (1.0f / (float)N_);
}

extern "C" void kernel_launch(void* const* d_in, const int* in_sizes, int n_in,
                              void* d_out, int out_size, void* d_ws, size_t ws_size,
                              hipStream_t stream) {
    const float* I = (const float*)d_in[0];   // y_true
    const float* J = (const float*)d_in[1];   // y_pred
    __half2* A = (__half2*)d_ws;               // 5*NH2
    __half2* B = A + 5 * NH2;                  // 5*NH2
    float* acc = (float*)(B + 5 * NH2);
    float* out = (float*)d_out;

    ncc_pass1<<<D_ * H_ / 2, 256, 0, stream>>>(I, J, A, acc);
    ncc_pass2<<<(5 * D_ * 4 * WP_) / 256, 256, 0, stream>>>(A, B);
    ncc_pass3<<<(HWP_ / 256) * (D_ / CH3), 256, 0, stream>>>(B, acc);
    ncc_finalize<<<1, 1, 0, stream>>>(acc, out);
}